// Round 1
// baseline (429.476 us; speedup 1.0000x reference)
//
#include <hip/hip_runtime.h>
#include <hip/hip_bf16.h>

#define N_NODES 50000
#define N_EDGES 800000
#define FDIM 64

// ---------------- workspace layout (4-byte element offsets) ----------------
// DIS: deg then dis (in-place)        [0, 50000)
// CNT: in-degree histogram (int)      [50048, +50000)
// OFF: CSR offsets (int, 50001)       [100096, +50001)
// CUR: scatter cursors (int)          [150144, +50000)
// BSUM: scan block sums (int)         [200192, +128)
// SROW: CSR source rows (int)         [200320, +800000)
// SNRM: CSR edge norms (float)        [1000320, +800000)
// TX1: prop1 result                   [1800320, +3200000)
// TX2: prop2 result                   [5000320, +3200000)
// total 8,200,320 elems = 32.8 MB
constexpr int DIS_O  = 0;
constexpr int CNT_O  = 50048;
constexpr int OFF_O  = 100096;
constexpr int CUR_O  = 150144;
constexpr int BSUM_O = 200192;
constexpr int SROW_O = 200320;
constexpr int SNRM_O = 1000320;
constexpr int TX1_O  = 1800320;
constexpr int TX2_O  = 5000320;

__device__ __forceinline__ unsigned short f32_to_bf16(float f) {
    unsigned u = __float_as_uint(f);
    u += 0x7fffu + ((u >> 16) & 1u);   // round-to-nearest-even
    return (unsigned short)(u >> 16);
}

// ---- 1. histogram: deg[row] += w ; cnt[col] += 1 ----
__global__ void k_hist(const int* __restrict__ ei, const float* __restrict__ ew,
                       float* __restrict__ deg, int* __restrict__ cnt) {
    int e = blockIdx.x * 256 + threadIdx.x;
    if (e < N_EDGES) {
        int r = ei[e];
        int c = ei[N_EDGES + e];
        atomicAdd(&deg[r], ew[e]);
        atomicAdd(&cnt[c], 1);
    }
}

// ---- 2. deg -> dis = rsqrt(deg) (in place) ----
__global__ void k_dis(float* __restrict__ dis) {
    int i = blockIdx.x * 256 + threadIdx.x;
    if (i < N_NODES) {
        float d = dis[i];
        dis[i] = d > 0.f ? rsqrtf(d) : 0.f;
    }
}

// ---- 3a. per-block exclusive scan of cnt (512/block) ----
__global__ void k_scan_a(const int* __restrict__ cnt, int* __restrict__ off,
                         int* __restrict__ bsum) {
    __shared__ int s[512];
    int t = threadIdx.x;
    int i = blockIdx.x * 512 + t;
    int v = (i < N_NODES) ? cnt[i] : 0;
    s[t] = v;
    __syncthreads();
    for (int o = 1; o < 512; o <<= 1) {
        int u = (t >= o) ? s[t - o] : 0;
        __syncthreads();
        s[t] += u;
        __syncthreads();
    }
    if (i < N_NODES) off[i] = s[t] - v;     // exclusive
    if (t == 511) bsum[blockIdx.x] = s[511]; // block total
}

// ---- 3b. exclusive scan of the 98 block sums ----
__global__ void k_scan_b(int* __restrict__ bsum, int nb) {
    __shared__ int s[128];
    int t = threadIdx.x;
    int v = (t < nb) ? bsum[t] : 0;
    s[t] = v;
    __syncthreads();
    for (int o = 1; o < 128; o <<= 1) {
        int u = (t >= o) ? s[t - o] : 0;
        __syncthreads();
        s[t] += u;
        __syncthreads();
    }
    if (t < nb) bsum[t] = s[t] - v;
}

// ---- 3c. add block offsets; also init cursors; off[N]=E ----
__global__ void k_scan_c(int* __restrict__ off, const int* __restrict__ bsum,
                         int* __restrict__ cur) {
    int t = threadIdx.x;
    int i = blockIdx.x * 512 + t;
    if (i < N_NODES) {
        int v = off[i] + bsum[blockIdx.x];
        off[i] = v;
        cur[i] = v;
    }
    if (i == 0) off[N_NODES] = N_EDGES;
}

// ---- 4. scatter edges into CSR buckets, fuse norm computation ----
__global__ void k_scatter(const int* __restrict__ ei, const float* __restrict__ ew,
                          const float* __restrict__ dis, int* __restrict__ cur,
                          int* __restrict__ srow, float* __restrict__ snrm) {
    int e = blockIdx.x * 256 + threadIdx.x;
    if (e < N_EDGES) {
        int r = ei[e];
        int c = ei[N_EDGES + e];
        float nm = -dis[r] * ew[e] * dis[c];
        int pos = atomicAdd(&cur[c], 1);
        srow[pos] = r;
        snrm[pos] = nm;
    }
}

// ---- 5. gather propagation: one wave per node, lane = feature ----
// mode 0: dst = sum norm*src[row]          (tx1)
// mode 1: dst = 2*sum norm*src[row] - sub  (tx2)
__global__ __launch_bounds__(256) void k_prop(
    const int* __restrict__ off, const int* __restrict__ srow,
    const float* __restrict__ snrm, const float* __restrict__ src,
    const float* __restrict__ sub, float* __restrict__ dst, int mode) {
    int node = (blockIdx.x * 256 + threadIdx.x) >> 6;
    int lane = threadIdx.x & 63;
    if (node >= N_NODES) return;
    int e = off[node];
    int end = off[node + 1];
    float acc = 0.f;
    for (; e + 3 < end; e += 4) {   // unroll x4 for gather ILP
        int   r0 = srow[e],     r1 = srow[e + 1], r2 = srow[e + 2], r3 = srow[e + 3];
        float a0 = snrm[e],     a1 = snrm[e + 1], a2 = snrm[e + 2], a3 = snrm[e + 3];
        float v0 = src[r0 * FDIM + lane], v1 = src[r1 * FDIM + lane];
        float v2 = src[r2 * FDIM + lane], v3 = src[r3 * FDIM + lane];
        acc += a0 * v0 + a1 * v1 + a2 * v2 + a3 * v3;
    }
    for (; e < end; ++e) acc += snrm[e] * src[srow[e] * FDIM + lane];
    if (mode == 0) dst[node * FDIM + lane] = acc;
    else           dst[node * FDIM + lane] = 2.f * acc - sub[node * FDIM + lane];
}

// ---- 6. fused dual-gate GEMM + GRU combine + linear head ----
// pre_z = [x,tx1,tx2] @ Wxz_cat + bxz + bhz ; pre_h likewise
// z = sigmoid(pre_z); ht = tanh(pre_h); h = (1-z)*ht
// out = sigmoid(tanh(h) @ Wlin + blin)
#define NPB 16  // nodes per block (4 waves x 4 nodes)
__global__ __launch_bounds__(256) void k_gemm(
    const float* __restrict__ x, const float* __restrict__ tx1,
    const float* __restrict__ tx2,
    const float* __restrict__ Wxz, const float* __restrict__ Wxh,
    const float* __restrict__ bxz, const float* __restrict__ bhz,
    const float* __restrict__ bxh, const float* __restrict__ bhh,
    const float* __restrict__ Wlin, const float* __restrict__ blin,
    float* __restrict__ out) {
    // weights bf16-packed along k: [k2][f], 96*64 u32 per gate = 24 KB each
    __shared__ unsigned wzp[96 * 64];
    __shared__ unsigned whp[96 * 64];
    __shared__ __align__(16) float ins[NPB * 192];  // 12 KB fp32 inputs
    int tid = threadIdx.x;

    for (int idx = tid; idx < 96 * 64; idx += 256) {
        int k2 = idx >> 6, f = idx & 63;
        float z0 = Wxz[(2 * k2) * 64 + f], z1 = Wxz[(2 * k2 + 1) * 64 + f];
        float h0 = Wxh[(2 * k2) * 64 + f], h1 = Wxh[(2 * k2 + 1) * 64 + f];
        wzp[idx] = (unsigned)f32_to_bf16(z0) | ((unsigned)f32_to_bf16(z1) << 16);
        whp[idx] = (unsigned)f32_to_bf16(h0) | ((unsigned)f32_to_bf16(h1) << 16);
    }
    int n0 = blockIdx.x * NPB;
    for (int idx = tid; idx < NPB * 192; idx += 256) {
        int nl = idx / 192, k = idx - nl * 192;
        int g = n0 + nl;
        float v = 0.f;
        if (g < N_NODES) {
            if (k < 64)       v = x[g * FDIM + k];
            else if (k < 128) v = tx1[g * FDIM + k - 64];
            else              v = tx2[g * FDIM + k - 128];
        }
        ins[idx] = v;
    }
    __syncthreads();

    int wave = tid >> 6, lane = tid & 63;
    float accz[4] = {0.f, 0.f, 0.f, 0.f};
    float acch[4] = {0.f, 0.f, 0.f, 0.f};
    const float2* insv = (const float2*)ins;  // 96 float2 per node row
    for (int k2 = 0; k2 < 96; ++k2) {
        unsigned pz = wzp[k2 * 64 + lane];
        unsigned ph = whp[k2 * 64 + lane];
        float wz0 = __uint_as_float(pz << 16);
        float wz1 = __uint_as_float(pz & 0xffff0000u);
        float wh0 = __uint_as_float(ph << 16);
        float wh1 = __uint_as_float(ph & 0xffff0000u);
#pragma unroll
        for (int j = 0; j < 4; ++j) {
            float2 iv = insv[(wave * 4 + j) * 96 + k2];  // wave-uniform -> LDS broadcast
            accz[j] += iv.x * wz0 + iv.y * wz1;
            acch[j] += iv.x * wh0 + iv.y * wh1;
        }
    }

    float bz  = bxz[lane] + bhz[lane];
    float bh  = bxh[lane] + bhh[lane];
    float wl0 = Wlin[lane * 2 + 0], wl1 = Wlin[lane * 2 + 1];
    float bl0 = blin[0], bl1 = blin[1];
#pragma unroll
    for (int j = 0; j < 4; ++j) {
        int g = n0 + wave * 4 + j;
        float z  = 1.f / (1.f + __expf(-(accz[j] + bz)));
        float ht = tanhf(acch[j] + bh);
        float t  = tanhf((1.f - z) * ht);
        float p0 = t * wl0, p1 = t * wl1;
        for (int o = 32; o > 0; o >>= 1) {
            p0 += __shfl_xor(p0, o, 64);
            p1 += __shfl_xor(p1, o, 64);
        }
        if (lane == 0 && g < N_NODES) {
            float2 o2;
            o2.x = 1.f / (1.f + __expf(-(p0 + bl0)));
            o2.y = 1.f / (1.f + __expf(-(p1 + bl1)));
            ((float2*)out)[g] = o2;
        }
    }
}

extern "C" void kernel_launch(void* const* d_in, const int* in_sizes, int n_in,
                              void* d_out, int out_size, void* d_ws, size_t ws_size,
                              hipStream_t stream) {
    const float* x    = (const float*)d_in[0];
    const int*   ei   = (const int*)d_in[1];
    const float* ew   = (const float*)d_in[2];
    const float* Wxz  = (const float*)d_in[3];
    const float* bxz  = (const float*)d_in[4];
    const float* bhz  = (const float*)d_in[6];
    const float* Wxh  = (const float*)d_in[11];
    const float* bxh  = (const float*)d_in[12];
    const float* bhh  = (const float*)d_in[14];
    const float* Wlin = (const float*)d_in[15];
    const float* blin = (const float*)d_in[16];
    float* out = (float*)d_out;

    float* ws   = (float*)d_ws;
    float* dis  = ws + DIS_O;
    int*   cnt  = (int*)(ws + CNT_O);
    int*   off  = (int*)(ws + OFF_O);
    int*   cur  = (int*)(ws + CUR_O);
    int*   bsum = (int*)(ws + BSUM_O);
    int*   srow = (int*)(ws + SROW_O);
    float* snrm = ws + SNRM_O;
    float* tx1  = ws + TX1_O;
    float* tx2  = ws + TX2_O;

    // zero deg + cnt (contiguous prefix of ws)
    hipMemsetAsync(d_ws, 0, (size_t)(CNT_O + N_NODES) * 4, stream);

    k_hist<<<(N_EDGES + 255) / 256, 256, 0, stream>>>(ei, ew, dis, cnt);
    k_dis<<<(N_NODES + 255) / 256, 256, 0, stream>>>(dis);
    const int nb = (N_NODES + 511) / 512;  // 98
    k_scan_a<<<nb, 512, 0, stream>>>(cnt, off, bsum);
    k_scan_b<<<1, 128, 0, stream>>>(bsum, nb);
    k_scan_c<<<nb, 512, 0, stream>>>(off, bsum, cur);
    k_scatter<<<(N_EDGES + 255) / 256, 256, 0, stream>>>(ei, ew, dis, cur, srow, snrm);
    k_prop<<<(N_NODES + 3) / 4, 256, 0, stream>>>(off, srow, snrm, x, nullptr, tx1, 0);
    k_prop<<<(N_NODES + 3) / 4, 256, 0, stream>>>(off, srow, snrm, tx1, x, tx2, 1);
    k_gemm<<<(N_NODES + NPB - 1) / NPB, 256, 0, stream>>>(
        x, tx1, tx2, Wxz, Wxh, bxz, bhz, bxh, bhh, Wlin, blin, out);
}

// Round 2
// 310.175 us; speedup vs baseline: 1.3846x; 1.3846x over previous
//
#include <hip/hip_runtime.h>
#include <hip/hip_bf16.h>

#define N_NODES 50000
#define N_EDGES 800000

typedef unsigned short ushort_t;
typedef __attribute__((ext_vector_type(8))) short bf16x8;
typedef __attribute__((ext_vector_type(4))) float f32x4;

// ---------------- workspace layout (4-byte word offsets) ----------------
constexpr int DIS_O  = 0;          // float[50000] deg -> dis in place
constexpr int CNT_O  = 50048;      // int[50000]   in-degree histogram
constexpr int OFF_O  = 100096;     // int[50001]   CSR offsets
constexpr int CUR_O  = 150144;     // int[50000]   scatter cursors
constexpr int BSUM_O = 200192;     // int[128]     scan block sums
constexpr int SROW_O = 200320;     // int[800000]  CSR source rows
constexpr int SNRM_O = 1000320;    // float[800000] CSR edge norms
constexpr int ABUF_O = 1800320;    // ushort[50000*192] = uint[50000*96]  A = [x|tx1|tx2] bf16
constexpr int PBUF_O = 6600320;    // ushort[24576]  B packed in MFMA fragment order
// total 6,612,608 words = 26.5 MB

__device__ __forceinline__ ushort_t f32_to_bf16(float f) {
    unsigned u = __float_as_uint(f);
    u += 0x7fffu + ((u >> 16) & 1u);   // round-to-nearest-even
    return (ushort_t)(u >> 16);
}
__device__ __forceinline__ float bflo(unsigned u) { return __uint_as_float(u << 16); }
__device__ __forceinline__ float bfhi(unsigned u) { return __uint_as_float(u & 0xffff0000u); }
__device__ __forceinline__ unsigned packbf2(float a, float b) {
    return (unsigned)f32_to_bf16(a) | ((unsigned)f32_to_bf16(b) << 16);
}
__device__ __forceinline__ float fsigmoid(float x) { return 1.f / (1.f + __expf(-x)); }
__device__ __forceinline__ float ftanh(float x) {
    x = fminf(15.f, fmaxf(-15.f, x));
    float e = __expf(2.f * x);
    return (e - 1.f) / (e + 1.f);
}

// ---- 1. histogram: deg[row] += w ; cnt[col] += 1 ----
__global__ void k_hist(const int* __restrict__ ei, const float* __restrict__ ew,
                       float* __restrict__ deg, int* __restrict__ cnt) {
    int e = blockIdx.x * 256 + threadIdx.x;
    if (e < N_EDGES) {
        atomicAdd(&deg[ei[e]], ew[e]);
        atomicAdd(&cnt[ei[N_EDGES + e]], 1);
    }
}

// ---- 2. deg -> dis = rsqrt(deg) ----
__global__ void k_dis(float* __restrict__ dis) {
    int i = blockIdx.x * 256 + threadIdx.x;
    if (i < N_NODES) {
        float d = dis[i];
        dis[i] = d > 0.f ? rsqrtf(d) : 0.f;
    }
}

// ---- 3a. per-block exclusive scan of cnt ----
__global__ void k_scan_a(const int* __restrict__ cnt, int* __restrict__ off,
                         int* __restrict__ bsum) {
    __shared__ int s[512];
    int t = threadIdx.x;
    int i = blockIdx.x * 512 + t;
    int v = (i < N_NODES) ? cnt[i] : 0;
    s[t] = v;
    __syncthreads();
    for (int o = 1; o < 512; o <<= 1) {
        int u = (t >= o) ? s[t - o] : 0;
        __syncthreads();
        s[t] += u;
        __syncthreads();
    }
    if (i < N_NODES) off[i] = s[t] - v;
    if (t == 511) bsum[blockIdx.x] = s[511];
}

// ---- 3b. scan the block sums ----
__global__ void k_scan_b(int* __restrict__ bsum, int nb) {
    __shared__ int s[128];
    int t = threadIdx.x;
    int v = (t < nb) ? bsum[t] : 0;
    s[t] = v;
    __syncthreads();
    for (int o = 1; o < 128; o <<= 1) {
        int u = (t >= o) ? s[t - o] : 0;
        __syncthreads();
        s[t] += u;
        __syncthreads();
    }
    if (t < nb) bsum[t] = s[t] - v;
}

// ---- 3c. add block offsets, init cursors ----
__global__ void k_scan_c(int* __restrict__ off, const int* __restrict__ bsum,
                         int* __restrict__ cur) {
    int t = threadIdx.x;
    int i = blockIdx.x * 512 + t;
    if (i < N_NODES) {
        int v = off[i] + bsum[blockIdx.x];
        off[i] = v;
        cur[i] = v;
    }
    if (i == 0) off[N_NODES] = N_EDGES;
}

// ---- 4. scatter edges into CSR buckets with fused norm ----
__global__ void k_scatter(const int* __restrict__ ei, const float* __restrict__ ew,
                          const float* __restrict__ dis, int* __restrict__ cur,
                          int* __restrict__ srow, float* __restrict__ snrm) {
    int e = blockIdx.x * 256 + threadIdx.x;
    if (e < N_EDGES) {
        int r = ei[e];
        int c = ei[N_EDGES + e];
        float nm = -dis[r] * ew[e] * dis[c];
        int pos = atomicAdd(&cur[c], 1);
        srow[pos] = r;
        snrm[pos] = nm;
    }
}

// ---- 5. x fp32 -> bf16 into A buffer cols [0,64) ----
__global__ void k_xcast(const float* __restrict__ x, unsigned* __restrict__ abuf) {
    int tid = blockIdx.x * 256 + threadIdx.x;   // 50000*32
    if (tid < N_NODES * 32) {
        int n = tid >> 5, f2 = tid & 31;
        float2 xv = ((const float2*)x)[tid];
        abuf[n * 96 + f2] = packbf2(xv.x, xv.y);
    }
}

// ---- 6. pack B = [Wxz | Wxh] (192x128 fp32) into MFMA fragment order, bf16 ----
// packed[((c*6+s)*64 + l)*8 + j] = B[k = s*32 + (l>>4)*8 + j][n = c*16 + (l&15)]
__global__ void k_packB(const float* __restrict__ Wxz, const float* __restrict__ Wxh,
                        ushort_t* __restrict__ pbuf) {
    int idx = blockIdx.x * 256 + threadIdx.x;   // 192*128
    if (idx < 24576) {
        int k = idx >> 7, n = idx & 127;
        float v = (n < 64) ? Wxz[k * 64 + n] : Wxh[k * 64 + (n - 64)];
        int c = n >> 4, s = k >> 5, l = (((k >> 3) & 3) << 4) | (n & 15), j = k & 7;
        pbuf[((c * 6 + s) * 64 + l) * 8 + j] = f32_to_bf16(v);
    }
}

// ---- 7. gather propagation, bf16, 2 edges in flight per wave (half-wave split) ----
// lanes 0-31 handle even edges, 32-63 odd; each lane covers features {2q, 2q+1}
// mode 0: dst = sum norm*src[row]          (tx1 <- x)
// mode 1: dst = 2*sum norm*src[row] - x32  (tx2, subtract fp32 x)
__global__ __launch_bounds__(256) void k_prop(
    const int* __restrict__ off, const int* __restrict__ srow,
    const float* __restrict__ snrm, const unsigned* __restrict__ abuf,
    const float* __restrict__ xf, unsigned* __restrict__ abw,
    int srcw, int dstw, int mode) {
    int node = (blockIdx.x * 256 + threadIdx.x) >> 6;
    if (node >= N_NODES) return;
    int lane = threadIdx.x & 63;
    int h = lane >> 5, q = lane & 31;
    int b = off[node], end = off[node + 1];
    float acc0 = 0.f, acc1 = 0.f;
    for (; b + 7 < end; b += 8) {                     // 8 edges per trip, 4 per half
        int e0 = b + h, e1 = b + h + 2, e2 = b + h + 4, e3 = b + h + 6;
        int   r0 = srow[e0], r1 = srow[e1], r2 = srow[e2], r3 = srow[e3];
        float a0 = snrm[e0], a1 = snrm[e1], a2 = snrm[e2], a3 = snrm[e3];
        unsigned v0 = abuf[r0 * 96 + srcw + q], v1 = abuf[r1 * 96 + srcw + q];
        unsigned v2 = abuf[r2 * 96 + srcw + q], v3 = abuf[r3 * 96 + srcw + q];
        acc0 += a0 * bflo(v0) + a1 * bflo(v1) + a2 * bflo(v2) + a3 * bflo(v3);
        acc1 += a0 * bfhi(v0) + a1 * bfhi(v1) + a2 * bfhi(v2) + a3 * bfhi(v3);
    }
    for (; b + 1 < end; b += 2) {
        int e = b + h;
        int r = srow[e]; float a = snrm[e];
        unsigned v = abuf[r * 96 + srcw + q];
        acc0 += a * bflo(v); acc1 += a * bfhi(v);
    }
    if (b < end && h == 0) {                          // odd leftover edge
        int r = srow[b]; float a = snrm[b];
        unsigned v = abuf[r * 96 + srcw + q];
        acc0 += a * bflo(v); acc1 += a * bfhi(v);
    }
    acc0 += __shfl_xor(acc0, 32, 64);
    acc1 += __shfl_xor(acc1, 32, 64);
    if (h == 0) {
        if (mode == 1) {
            float2 xv = ((const float2*)xf)[node * 32 + q];
            acc0 = 2.f * acc0 - xv.x;
            acc1 = 2.f * acc1 - xv.y;
        }
        abw[node * 96 + dstw + q] = packbf2(acc0, acc1);
    }
}

// ---- 8. MFMA GEMM [50000x192]@[192x128] + GRU combine + linear head ----
// 64 nodes/block: 4 waves x 16 rows. A loaded straight from global in frag layout.
__global__ __launch_bounds__(256) void k_gemm(
    const ushort_t* __restrict__ ab, const ushort_t* __restrict__ pbuf,
    const float* __restrict__ bxz, const float* __restrict__ bhz,
    const float* __restrict__ bxh, const float* __restrict__ bhh,
    const float* __restrict__ Wlin, const float* __restrict__ blin,
    float2* __restrict__ out) {
    __shared__ ushort_t bsh[24576];   // 48 KB packed B
    int tid = threadIdx.x;
    {
        uint4* s4 = (uint4*)bsh;
        const uint4* g4 = (const uint4*)pbuf;
        for (int i = tid; i < 3072; i += 256) s4[i] = g4[i];
    }
    __syncthreads();

    int wave = tid >> 6, lane = tid & 63;
    int quad = lane >> 4, m = lane & 15;
    int arow = blockIdx.x * 64 + wave * 16 + m;       // A-operand row for this lane
    const ushort_t* ap = ab + (size_t)arow * 192 + quad * 8;

    f32x4 acc[8];
#pragma unroll
    for (int c = 0; c < 8; ++c) acc[c] = (f32x4){0.f, 0.f, 0.f, 0.f};

#pragma unroll
    for (int s = 0; s < 6; ++s) {
        bf16x8 af = *(const bf16x8*)(ap + s * 32);
#pragma unroll
        for (int c = 0; c < 8; ++c) {
            bf16x8 bfr = *(const bf16x8*)(bsh + ((c * 6 + s) * 64 + lane) * 8);
            acc[c] = __builtin_amdgcn_mfma_f32_16x16x32_bf16(af, bfr, acc[c], 0, 0, 0);
        }
    }

    // per-lane epilogue constants (cols c*16 + m)
    float bzv[4], bhv[4], wl0[4], wl1[4];
#pragma unroll
    for (int c = 0; c < 4; ++c) {
        int col = c * 16 + m;
        bzv[c] = bxz[col] + bhz[col];
        bhv[c] = bxh[col] + bhh[col];
        wl0[c] = Wlin[2 * col];
        wl1[c] = Wlin[2 * col + 1];
    }
    float bl0 = blin[0], bl1 = blin[1];

#pragma unroll
    for (int i = 0; i < 4; ++i) {                     // C/D row = quad*4 + i
        float p0 = 0.f, p1 = 0.f;
#pragma unroll
        for (int c = 0; c < 4; ++c) {                 // z tile c pairs with h tile c+4
            float z  = fsigmoid(acc[c][i] + bzv[c]);
            float ht = ftanh(acc[c + 4][i] + bhv[c]);
            float t  = ftanh((1.f - z) * ht);
            p0 += t * wl0[c];
            p1 += t * wl1[c];
        }
        for (int o = 1; o <= 8; o <<= 1) {            // reduce 64 cols across 16 lanes
            p0 += __shfl_xor(p0, o, 64);
            p1 += __shfl_xor(p1, o, 64);
        }
        int g = blockIdx.x * 64 + wave * 16 + quad * 4 + i;
        if (m == 0 && g < N_NODES)
            out[g] = make_float2(fsigmoid(p0 + bl0), fsigmoid(p1 + bl1));
    }
}

extern "C" void kernel_launch(void* const* d_in, const int* in_sizes, int n_in,
                              void* d_out, int out_size, void* d_ws, size_t ws_size,
                              hipStream_t stream) {
    const float* x    = (const float*)d_in[0];
    const int*   ei   = (const int*)d_in[1];
    const float* ew   = (const float*)d_in[2];
    const float* Wxz  = (const float*)d_in[3];
    const float* bxz  = (const float*)d_in[4];
    const float* bhz  = (const float*)d_in[6];
    const float* Wxh  = (const float*)d_in[11];
    const float* bxh  = (const float*)d_in[12];
    const float* bhh  = (const float*)d_in[14];
    const float* Wlin = (const float*)d_in[15];
    const float* blin = (const float*)d_in[16];

    float*    ws   = (float*)d_ws;
    float*    dis  = ws + DIS_O;
    int*      cnt  = (int*)(ws + CNT_O);
    int*      off  = (int*)(ws + OFF_O);
    int*      cur  = (int*)(ws + CUR_O);
    int*      bsum = (int*)(ws + BSUM_O);
    int*      srow = (int*)(ws + SROW_O);
    float*    snrm = ws + SNRM_O;
    unsigned* abuf = (unsigned*)(ws + ABUF_O);
    ushort_t* pbuf = (ushort_t*)(ws + PBUF_O);

    hipMemsetAsync(d_ws, 0, (size_t)(CNT_O + N_NODES) * 4, stream);   // deg + cnt

    k_hist<<<(N_EDGES + 255) / 256, 256, 0, stream>>>(ei, ew, dis, cnt);
    k_dis<<<(N_NODES + 255) / 256, 256, 0, stream>>>(dis);
    const int nb = (N_NODES + 511) / 512;  // 98
    k_scan_a<<<nb, 512, 0, stream>>>(cnt, off, bsum);
    k_scan_b<<<1, 128, 0, stream>>>(bsum, nb);
    k_scan_c<<<nb, 512, 0, stream>>>(off, bsum, cur);
    k_scatter<<<(N_EDGES + 255) / 256, 256, 0, stream>>>(ei, ew, dis, cur, srow, snrm);
    k_xcast<<<(N_NODES * 32 + 255) / 256, 256, 0, stream>>>(x, abuf);
    k_packB<<<96, 256, 0, stream>>>(Wxz, Wxh, pbuf);
    k_prop<<<(N_NODES + 3) / 4, 256, 0, stream>>>(off, srow, snrm, abuf, x, abuf, 0, 32, 0);
    k_prop<<<(N_NODES + 3) / 4, 256, 0, stream>>>(off, srow, snrm, abuf, x, abuf, 32, 64, 1);
    k_gemm<<<(N_NODES + 63) / 64, 256, 0, stream>>>(
        (const ushort_t*)abuf, pbuf, bxz, bhz, bxh, bhh, Wlin, blin, (float2*)d_out);
}

// Round 3
// 264.339 us; speedup vs baseline: 1.6247x; 1.1734x over previous
//
#include <hip/hip_runtime.h>
#include <hip/hip_bf16.h>

#define N_NODES 50000
#define N_EDGES 800000
#define NB1 400       // k1 bucketing blocks
#define CH  2000      // edges per k1 block (NB1*CH == N_EDGES)
#define NBKT 196      // MSD buckets = col>>8
#define CAP 8192      // slots per bucket (expected 4082, sigma 64)
#define SORT_MAX 6144 // LDS sort capacity per bucket

typedef unsigned short ushort_t;
typedef unsigned long long u64;
typedef __attribute__((ext_vector_type(8))) short bf16x8;
typedef __attribute__((ext_vector_type(4))) float f32x4;

// ---------------- workspace layout (4-byte word offsets) ----------------
constexpr int DEG_O   = 0;          // float[50000]
constexpr int GCUR_O  = 50000;      // uint[196] bucket cursors (zeroed with deg)
constexpr int DIS_O   = 50304;      // float[50000]
constexpr int OFF_O   = 100352;     // int[50001] CSR offsets
constexpr int SLOTS_O = 150528;     // uint[196*8192] bucket slots; reused as T1S after k2
constexpr int RW_O    = 1756160;    // u64[800000] final CSR payload (row,w)
constexpr int XS_O    = 3356160;    // uint[50000*32] xs = dis*x bf16x2
constexpr int ABUF_O  = 4956160;    // uint[50000*96] A=[x|tx1|tx2] bf16x2
constexpr int PBUF_O  = 9756160;    // ushort[24576] packed B
// total ~9.77M words = 39.1 MB
constexpr int T1S_O   = SLOTS_O;    // uint[50000*32] dis*tx1 (slots dead after k2)

__device__ __forceinline__ ushort_t f32_to_bf16(float f) {
    unsigned u = __float_as_uint(f);
    u += 0x7fffu + ((u >> 16) & 1u);
    return (ushort_t)(u >> 16);
}
__device__ __forceinline__ float bflo(unsigned u) { return __uint_as_float(u << 16); }
__device__ __forceinline__ float bfhi(unsigned u) { return __uint_as_float(u & 0xffff0000u); }
__device__ __forceinline__ unsigned packbf2(float a, float b) {
    return (unsigned)f32_to_bf16(a) | ((unsigned)f32_to_bf16(b) << 16);
}
__device__ __forceinline__ float fsigmoid(float x) { return 1.f / (1.f + __expf(-x)); }
__device__ __forceinline__ float ftanh(float x) {
    x = fminf(15.f, fmaxf(-15.f, x));
    float e = __expf(2.f * x);
    return (e - 1.f) / (e + 1.f);
}

// ---- k1: MSD bucketing (col>>8) + deg atomics + plain-x cast + packB ----
__global__ __launch_bounds__(256) void k1(
    const int* __restrict__ ei, const float* __restrict__ ew,
    const float* __restrict__ x, const float* __restrict__ Wxz,
    const float* __restrict__ Wxh, float* __restrict__ deg,
    unsigned* __restrict__ gcur, unsigned* __restrict__ slots,
    unsigned* __restrict__ abuf, ushort_t* __restrict__ pbuf) {
    int bid = blockIdx.x, t = threadIdx.x;
    if (bid < NB1) {
        __shared__ unsigned colbuf[CH];
        __shared__ unsigned hist[256], basec[256];
        hist[t] = 0;
        __syncthreads();
        int e0 = bid * CH;
        for (int i = t; i < CH; i += 256) {
            int e = e0 + i;
            unsigned c = (unsigned)ei[N_EDGES + e];
            colbuf[i] = c;
            atomicAdd(&hist[c >> 8], 1u);
            atomicAdd(&deg[ei[e]], ew[e]);   // 800k device atomics: the real cost
        }
        __syncthreads();
        if (t < NBKT) basec[t] = atomicAdd(&gcur[t], hist[t]);  // 196/block
        __syncthreads();
        hist[t] = 0;   // reuse as local cursor
        __syncthreads();
        for (int i = t; i < CH; i += 256) {
            unsigned c = colbuf[i];
            unsigned d = c >> 8;
            unsigned p = basec[d] + atomicAdd(&hist[d], 1u);
            if (p < CAP) slots[d * CAP + p] = ((c & 255u) << 24) | (unsigned)(e0 + i);
        }
    } else if (bid < NB1 + 98) {             // plain-x bf16 cast into A cols [0,64)
        int n0 = (bid - NB1) * 512;
        for (int idx = t; idx < 512 * 32; idx += 256) {
            int n = n0 + (idx >> 5);
            if (n < N_NODES) {
                int q = idx & 31;
                float2 xv = ((const float2*)x)[n * 32 + q];
                abuf[n * 96 + q] = packbf2(xv.x, xv.y);
            }
        }
    } else {                                 // pack B into MFMA fragment order
        for (int idx = t; idx < 24576; idx += 256) {
            int k = idx >> 7, n = idx & 127;
            float v = (n < 64) ? Wxz[k * 64 + n] : Wxh[k * 64 + (n - 64)];
            int c = n >> 4, s = k >> 5, l = (((k >> 3) & 3) << 4) | (n & 15), j = k & 7;
            pbuf[((c * 6 + s) * 64 + l) * 8 + j] = f32_to_bf16(v);
        }
    }
}

// ---- k2: in-LDS LSD sort per bucket -> off[] + (row,w) CSR; plus dis+xs ----
__global__ __launch_bounds__(512) void k2(
    const int* __restrict__ ei, const float* __restrict__ ew,
    const float* __restrict__ x, const float* __restrict__ deg,
    const unsigned* __restrict__ gcur, const unsigned* __restrict__ slots,
    float* __restrict__ dis, int* __restrict__ off,
    u64* __restrict__ rw, unsigned* __restrict__ xs) {
    int bid = blockIdx.x, t = threadIdx.x;
    if (bid < NBKT) {
        __shared__ unsigned raw[SORT_MAX], srt[SORT_MAX];
        __shared__ unsigned hist[256], hsc[256], cur[256], gs[256];
        if (t < 256) {
            gs[t] = (t < NBKT) ? gcur[t] : 0u;
            hist[t] = 0;
        }
        __syncthreads();
        for (int o = 1; o < 256; o <<= 1) {   // inclusive scan of bucket sizes
            unsigned v = (t < 256 && t >= o) ? gs[t - o] : 0u;
            __syncthreads();
            if (t < 256) gs[t] += v;
            __syncthreads();
        }
        unsigned szb = gcur[bid];
        unsigned sz = min(szb, (unsigned)SORT_MAX);
        unsigned base = gs[bid] - szb;        // exclusive prefix
        for (unsigned i = t; i < sz; i += 512) {
            unsigned v = slots[bid * CAP + i];
            raw[i] = v;
            atomicAdd(&hist[v >> 24], 1u);
        }
        __syncthreads();
        unsigned h0 = (t < 256) ? hist[t] : 0u;
        if (t < 256) hsc[t] = h0;
        __syncthreads();
        for (int o = 1; o < 256; o <<= 1) {   // inclusive scan of digit hist
            unsigned v = (t < 256 && t >= o) ? hsc[t - o] : 0u;
            __syncthreads();
            if (t < 256) hsc[t] += v;
            __syncthreads();
        }
        if (t < 256) {
            hsc[t] -= h0;                     // exclusive
            cur[t] = 0u;
            int c = bid * 256 + t;            // off for this bucket's 256 cols
            if (c <= N_NODES) off[c] = (int)(base + hsc[t]);
        }
        __syncthreads();
        for (unsigned i = t; i < sz; i += 512) {
            unsigned v = raw[i];
            unsigned d = v >> 24;
            unsigned p = hsc[d] + atomicAdd(&cur[d], 1u);
            srt[p] = v;
        }
        __syncthreads();
        for (unsigned i = t; i < sz; i += 512) {   // materialize (row, w)
            unsigned id = srt[i] & 0xFFFFFu;
            unsigned r = (unsigned)ei[id];
            float w = ew[id];
            rw[base + i] = ((u64)__float_as_uint(w) << 32) | (u64)r;
        }
    } else {                                  // dis = rsqrt(deg); xs = dis*x bf16
        int n0 = (bid - NBKT) * 512;
        for (int idx = t; idx < 512 * 32; idx += 512) {
            int n = n0 + (idx >> 5);
            if (n < N_NODES) {
                int q = idx & 31;
                float d = deg[n];
                float r = d > 0.f ? rsqrtf(d) : 0.f;
                if (q == 0) dis[n] = r;
                float2 xv = ((const float2*)x)[n * 32 + q];
                xs[n * 32 + q] = packbf2(r * xv.x, r * xv.y);
            }
        }
    }
}

// ---- prop: one wave per node; halves handle alternating edges ----
// mode 0: tx1 = -dis*sum(w*xs[row]); write abuf tx1 + t1s = dis*tx1
// mode 1: tx2 = 2*(-dis*sum(w*t1s[row])) - x(fp32); write abuf tx2
__global__ __launch_bounds__(256) void k_prop(
    const int* __restrict__ off, const u64* __restrict__ rw,
    const unsigned* __restrict__ xsrc, const float* __restrict__ dis,
    const float* __restrict__ xf, unsigned* __restrict__ abuf,
    unsigned* __restrict__ t1s, int mode) {
    int node = (blockIdx.x * 256 + threadIdx.x) >> 6;
    if (node >= N_NODES) return;
    int lane = threadIdx.x & 63, h = lane >> 5, q = lane & 31;
    int b = off[node], end = off[node + 1];
    float acc0 = 0.f, acc1 = 0.f;
    for (; b + 7 < end; b += 8) {
        u64 v0 = rw[b + h], v1 = rw[b + h + 2], v2 = rw[b + h + 4], v3 = rw[b + h + 6];
        unsigned r0 = (unsigned)v0, r1 = (unsigned)v1, r2 = (unsigned)v2, r3 = (unsigned)v3;
        float a0 = __uint_as_float((unsigned)(v0 >> 32));
        float a1 = __uint_as_float((unsigned)(v1 >> 32));
        float a2 = __uint_as_float((unsigned)(v2 >> 32));
        float a3 = __uint_as_float((unsigned)(v3 >> 32));
        unsigned u0 = xsrc[r0 * 32 + q], u1 = xsrc[r1 * 32 + q];
        unsigned u2 = xsrc[r2 * 32 + q], u3 = xsrc[r3 * 32 + q];
        acc0 += a0 * bflo(u0) + a1 * bflo(u1) + a2 * bflo(u2) + a3 * bflo(u3);
        acc1 += a0 * bfhi(u0) + a1 * bfhi(u1) + a2 * bfhi(u2) + a3 * bfhi(u3);
    }
    for (; b + 1 < end; b += 2) {
        u64 v = rw[b + h];
        unsigned r = (unsigned)v;
        float a = __uint_as_float((unsigned)(v >> 32));
        unsigned u = xsrc[r * 32 + q];
        acc0 += a * bflo(u); acc1 += a * bfhi(u);
    }
    if (b < end && h == 0) {
        u64 v = rw[b];
        unsigned r = (unsigned)v;
        float a = __uint_as_float((unsigned)(v >> 32));
        unsigned u = xsrc[r * 32 + q];
        acc0 += a * bflo(u); acc1 += a * bfhi(u);
    }
    acc0 += __shfl_xor(acc0, 32, 64);
    acc1 += __shfl_xor(acc1, 32, 64);
    if (h == 0) {
        float di = dis[node];
        float t0 = -di * acc0, t1v = -di * acc1;
        if (mode == 0) {
            abuf[node * 96 + 32 + q] = packbf2(t0, t1v);
            t1s[node * 32 + q] = packbf2(di * t0, di * t1v);
        } else {
            float2 xv = ((const float2*)xf)[node * 32 + q];
            abuf[node * 96 + 64 + q] = packbf2(2.f * t0 - xv.x, 2.f * t1v - xv.y);
        }
    }
}

// ---- MFMA GEMM [50000x192]@[192x128] + GRU combine + head (unchanged) ----
__global__ __launch_bounds__(256) void k_gemm(
    const ushort_t* __restrict__ ab, const ushort_t* __restrict__ pbuf,
    const float* __restrict__ bxz, const float* __restrict__ bhz,
    const float* __restrict__ bxh, const float* __restrict__ bhh,
    const float* __restrict__ Wlin, const float* __restrict__ blin,
    float2* __restrict__ out) {
    __shared__ ushort_t bsh[24576];
    int tid = threadIdx.x;
    {
        uint4* s4 = (uint4*)bsh;
        const uint4* g4 = (const uint4*)pbuf;
        for (int i = tid; i < 3072; i += 256) s4[i] = g4[i];
    }
    __syncthreads();

    int wave = tid >> 6, lane = tid & 63;
    int quad = lane >> 4, m = lane & 15;
    int arow = blockIdx.x * 64 + wave * 16 + m;
    const ushort_t* ap = ab + (size_t)arow * 192 + quad * 8;

    f32x4 acc[8];
#pragma unroll
    for (int c = 0; c < 8; ++c) acc[c] = (f32x4){0.f, 0.f, 0.f, 0.f};
#pragma unroll
    for (int s = 0; s < 6; ++s) {
        bf16x8 af = *(const bf16x8*)(ap + s * 32);
#pragma unroll
        for (int c = 0; c < 8; ++c) {
            bf16x8 bfr = *(const bf16x8*)(bsh + ((c * 6 + s) * 64 + lane) * 8);
            acc[c] = __builtin_amdgcn_mfma_f32_16x16x32_bf16(af, bfr, acc[c], 0, 0, 0);
        }
    }
    float bzv[4], bhv[4], wl0[4], wl1[4];
#pragma unroll
    for (int c = 0; c < 4; ++c) {
        int col = c * 16 + m;
        bzv[c] = bxz[col] + bhz[col];
        bhv[c] = bxh[col] + bhh[col];
        wl0[c] = Wlin[2 * col];
        wl1[c] = Wlin[2 * col + 1];
    }
    float bl0 = blin[0], bl1 = blin[1];
#pragma unroll
    for (int i = 0; i < 4; ++i) {
        float p0 = 0.f, p1 = 0.f;
#pragma unroll
        for (int c = 0; c < 4; ++c) {
            float z  = fsigmoid(acc[c][i] + bzv[c]);
            float ht = ftanh(acc[c + 4][i] + bhv[c]);
            float t  = ftanh((1.f - z) * ht);
            p0 += t * wl0[c];
            p1 += t * wl1[c];
        }
        for (int o = 1; o <= 8; o <<= 1) {
            p0 += __shfl_xor(p0, o, 64);
            p1 += __shfl_xor(p1, o, 64);
        }
        int g = blockIdx.x * 64 + wave * 16 + quad * 4 + i;
        if (m == 0 && g < N_NODES)
            out[g] = make_float2(fsigmoid(p0 + bl0), fsigmoid(p1 + bl1));
    }
}

extern "C" void kernel_launch(void* const* d_in, const int* in_sizes, int n_in,
                              void* d_out, int out_size, void* d_ws, size_t ws_size,
                              hipStream_t stream) {
    const float* x    = (const float*)d_in[0];
    const int*   ei   = (const int*)d_in[1];
    const float* ew   = (const float*)d_in[2];
    const float* Wxz  = (const float*)d_in[3];
    const float* bxz  = (const float*)d_in[4];
    const float* bhz  = (const float*)d_in[6];
    const float* Wxh  = (const float*)d_in[11];
    const float* bxh  = (const float*)d_in[12];
    const float* bhh  = (const float*)d_in[14];
    const float* Wlin = (const float*)d_in[15];
    const float* blin = (const float*)d_in[16];

    float*    ws    = (float*)d_ws;
    float*    deg   = ws + DEG_O;
    unsigned* gcur  = (unsigned*)(ws + GCUR_O);
    float*    dis   = ws + DIS_O;
    int*      off   = (int*)(ws + OFF_O);
    unsigned* slots = (unsigned*)(ws + SLOTS_O);
    u64*      rw    = (u64*)(ws + RW_O);
    unsigned* xs    = (unsigned*)(ws + XS_O);
    unsigned* abuf  = (unsigned*)(ws + ABUF_O);
    ushort_t* pbuf  = (ushort_t*)(ws + PBUF_O);
    unsigned* t1s   = (unsigned*)(ws + T1S_O);

    // zero deg[50000] + gcur[196] (contiguous)
    hipMemsetAsync(d_ws, 0, (size_t)(GCUR_O + 256) * 4, stream);

    k1<<<NB1 + 98 + 1, 256, 0, stream>>>(ei, ew, x, Wxz, Wxh, deg, gcur, slots, abuf, pbuf);
    k2<<<NBKT + 98, 512, 0, stream>>>(ei, ew, x, deg, gcur, slots, dis, off, rw, xs);
    k_prop<<<12500, 256, 0, stream>>>(off, rw, xs, dis, x, abuf, t1s, 0);
    k_prop<<<12500, 256, 0, stream>>>(off, rw, t1s, dis, x, abuf, abuf, 1);
    k_gemm<<<782, 256, 0, stream>>>((const ushort_t*)abuf, pbuf, bxz, bhz, bxh, bhh,
                                    Wlin, blin, (float2*)d_out);
}

// Round 4
// 227.126 us; speedup vs baseline: 1.8909x; 1.1638x over previous
//
#include <hip/hip_runtime.h>
#include <hip/hip_bf16.h>

#define N_NODES 50000
#define N_EDGES 800000
#define NB1 200       // k1 bucketing blocks
#define CH  4000      // edges per k1 block (NB1*CH == N_EDGES)
#define NBKT 196      // MSD buckets = key>>8
#define CAP 8192      // slots per bucket (mean ~4082, 64 sigma headroom)
#define SORT_MAX 6144 // LDS sort capacity per bucket

typedef unsigned short ushort_t;
typedef unsigned long long u64;
typedef __attribute__((ext_vector_type(8))) short bf16x8;
typedef __attribute__((ext_vector_type(4))) float f32x4;

// ---------------- workspace layout (4-byte word offsets) ----------------
constexpr int GCUR_O  = 0;          // uint[512]: [0,196) col cursors, [256,452) row cursors
constexpr int DIS_O   = 512;        // float[50000]
constexpr int OFF_O   = 50512;      // int[50001]
constexpr int CSLOT_O = 100544;     // uint[196*8192] col buckets; reused as XS after k2
constexpr int RSLOT_O = 1706176;    // uint[196*8192] row buckets; reused as T1S after k2
constexpr int RW_O    = 3311808;    // u64[800000] CSR payload (w,row)
constexpr int ABUF_O  = 4911808;    // uint[50000*96] A=[x|tx1|tx2] bf16x2
constexpr int PBUF_O  = 9711808;    // ushort[24576] packed B
// total 9,724,096 words = 38.9 MB
constexpr int XS_O    = CSLOT_O;    // uint[50000*32] xs = dis*x  (aliases col slots)
constexpr int T1S_O   = RSLOT_O;    // uint[50000*32] dis*tx1    (aliases row slots)

__device__ __forceinline__ ushort_t f32_to_bf16(float f) {
    unsigned u = __float_as_uint(f);
    u += 0x7fffu + ((u >> 16) & 1u);
    return (ushort_t)(u >> 16);
}
__device__ __forceinline__ float bflo(unsigned u) { return __uint_as_float(u << 16); }
__device__ __forceinline__ float bfhi(unsigned u) { return __uint_as_float(u & 0xffff0000u); }
__device__ __forceinline__ unsigned packbf2(float a, float b) {
    return (unsigned)f32_to_bf16(a) | ((unsigned)f32_to_bf16(b) << 16);
}
__device__ __forceinline__ float fsigmoid(float x) { return 1.f / (1.f + __expf(-x)); }
__device__ __forceinline__ float ftanh(float x) {
    x = fminf(15.f, fmaxf(-15.f, x));
    float e = __expf(2.f * x);
    return (e - 1.f) / (e + 1.f);
}

// ---- k1: dual MSD bucketing (col for CSR, row for deg) + x cast + packB ----
// NO per-edge global atomics: only 392 cursor atomics per bucketing block.
__global__ __launch_bounds__(512) void k1(
    const int* __restrict__ ei, const float* __restrict__ ew,
    const float* __restrict__ x, const float* __restrict__ Wxz,
    const float* __restrict__ Wxh, unsigned* __restrict__ gcur,
    unsigned* __restrict__ cslot, unsigned* __restrict__ rslot,
    unsigned* __restrict__ abuf, ushort_t* __restrict__ pbuf) {
    int bid = blockIdx.x, t = threadIdx.x;
    if (bid < NB1) {
        __shared__ unsigned colbuf[CH], rowbuf[CH];
        __shared__ unsigned hc[256], hr[256], bc[256], br[256];
        if (t < 256) { hc[t] = 0; hr[t] = 0; }
        __syncthreads();
        int e0 = bid * CH;
        for (int i = t; i < CH; i += 512) {
            unsigned r = (unsigned)ei[e0 + i];
            unsigned c = (unsigned)ei[N_EDGES + e0 + i];
            rowbuf[i] = r;
            colbuf[i] = c;
            atomicAdd(&hc[c >> 8], 1u);
            atomicAdd(&hr[r >> 8], 1u);
        }
        __syncthreads();
        if (t < NBKT) {
            bc[t] = atomicAdd(&gcur[t], hc[t]);
            br[t] = atomicAdd(&gcur[256 + t], hr[t]);
        }
        __syncthreads();
        if (t < 256) { hc[t] = 0; hr[t] = 0; }   // reuse as local cursors
        __syncthreads();
        for (int i = t; i < CH; i += 512) {
            unsigned c = colbuf[i];
            unsigned dc = c >> 8;
            unsigned pc = bc[dc] + atomicAdd(&hc[dc], 1u);
            if (pc < CAP) cslot[dc * CAP + pc] = ((c & 255u) << 24) | (unsigned)(e0 + i);
            unsigned r = rowbuf[i];
            unsigned dr = r >> 8;
            unsigned w = __float_as_uint(ew[e0 + i]);
            unsigned pr = br[dr] + atomicAdd(&hr[dr], 1u);
            if (pr < CAP) rslot[dr * CAP + pr] = (w & 0xFFFFFF00u) | (r & 255u);
        }
    } else if (bid < NB1 + 98) {                 // plain-x bf16 cast into A cols [0,64)
        int n0 = (bid - NB1) * 512;
        for (int idx = t; idx < 512 * 32; idx += 512) {
            int n = n0 + (idx >> 5);
            if (n < N_NODES) {
                int q = idx & 31;
                float2 xv = ((const float2*)x)[n * 32 + q];
                abuf[n * 96 + q] = packbf2(xv.x, xv.y);
            }
        }
    } else {                                     // pack B into MFMA fragment order
        for (int idx = t; idx < 24576; idx += 512) {
            int k = idx >> 7, n = idx & 127;
            float v = (n < 64) ? Wxz[k * 64 + n] : Wxh[k * 64 + (n - 64)];
            int c = n >> 4, s = k >> 5, l = (((k >> 3) & 3) << 4) | (n & 15), j = k & 7;
            pbuf[((c * 6 + s) * 64 + l) * 8 + j] = f32_to_bf16(v);
        }
    }
}

// ---- k2: per-bucket LDS sort -> off+rw ; then deg/dis/xs for same 256 nodes ----
__global__ __launch_bounds__(512) void k2(
    const int* __restrict__ ei, const float* __restrict__ ew,
    const float* __restrict__ x, const unsigned* __restrict__ gcur,
    const unsigned* __restrict__ cslot, const unsigned* __restrict__ rslot,
    float* __restrict__ dis, int* __restrict__ off,
    u64* __restrict__ rw, unsigned* __restrict__ xs) {
    int bid = blockIdx.x, t = threadIdx.x;
    __shared__ unsigned raw[SORT_MAX], srt[SORT_MAX];
    __shared__ unsigned hist[256], hsc[256], cur[256], gs[256];
    __shared__ float facc[256];

    // ---- phase A: sort col bucket bid by col&255 -> off + (row,w) CSR ----
    if (t < 256) {
        gs[t] = (t < NBKT) ? gcur[t] : 0u;
        hist[t] = 0;
    }
    __syncthreads();
    for (int o = 1; o < 256; o <<= 1) {          // inclusive scan of bucket sizes
        unsigned v = (t < 256 && t >= o) ? gs[t - o] : 0u;
        __syncthreads();
        if (t < 256) gs[t] += v;
        __syncthreads();
    }
    unsigned szb = gcur[bid];
    unsigned sz = min(szb, (unsigned)SORT_MAX);
    unsigned base = gs[bid] - szb;               // exclusive prefix
    for (unsigned i = t; i < sz; i += 512) {
        unsigned v = cslot[bid * CAP + i];
        raw[i] = v;
        atomicAdd(&hist[v >> 24], 1u);
    }
    __syncthreads();
    unsigned h0 = (t < 256) ? hist[t] : 0u;
    if (t < 256) hsc[t] = h0;
    __syncthreads();
    for (int o = 1; o < 256; o <<= 1) {          // inclusive scan of digit hist
        unsigned v = (t < 256 && t >= o) ? hsc[t - o] : 0u;
        __syncthreads();
        if (t < 256) hsc[t] += v;
        __syncthreads();
    }
    if (t < 256) {
        hsc[t] -= h0;                            // exclusive
        cur[t] = 0u;
        int c = bid * 256 + t;
        if (c <= N_NODES) off[c] = (int)(base + hsc[t]);
    }
    __syncthreads();
    for (unsigned i = t; i < sz; i += 512) {
        unsigned v = raw[i];
        unsigned d = v >> 24;
        unsigned p = hsc[d] + atomicAdd(&cur[d], 1u);
        srt[p] = v;
    }
    __syncthreads();
    for (unsigned i = t; i < sz; i += 512) {     // materialize (row, w)
        unsigned id = srt[i] & 0xFFFFFu;
        unsigned r = (unsigned)ei[id];
        float w = ew[id];
        rw[base + i] = ((u64)__float_as_uint(w) << 32) | (u64)r;
    }
    __syncthreads();

    // ---- phase B: deg for rows [bid*256, +256) from row bucket, dis, xs ----
    if (t < 256) facc[t] = 0.f;
    __syncthreads();
    unsigned szr = min(gcur[256 + bid], (unsigned)CAP);
    for (unsigned i = t; i < szr; i += 512) {
        unsigned v = rslot[bid * CAP + i];
        atomicAdd(&facc[v & 255u], __uint_as_float(v & 0xFFFFFF00u));
    }
    __syncthreads();
    if (t < 256) {
        float d = facc[t];
        float r = d > 0.f ? rsqrtf(d) : 0.f;
        facc[t] = r;
        int n = bid * 256 + t;
        if (n < N_NODES) dis[n] = r;
    }
    __syncthreads();
    for (int idx = t; idx < 8192; idx += 512) {  // xs = dis*x, overwrites own col bucket
        int nl = idx >> 5, q = idx & 31;
        int n = bid * 256 + nl;
        if (n < N_NODES) {
            float2 xv = ((const float2*)x)[n * 32 + q];
            float r = facc[nl];
            xs[n * 32 + q] = packbf2(r * xv.x, r * xv.y);
        }
    }
}

// ---- prop: one wave per node; halves handle alternating edges ----
// mode 0: tx1 = -dis*sum(w*xs[row]); write abuf tx1 + t1s = dis*tx1
// mode 1: tx2 = 2*(-dis*sum(w*t1s[row])) - x(fp32); write abuf tx2
__global__ __launch_bounds__(256) void k_prop(
    const int* __restrict__ off, const u64* __restrict__ rw,
    const unsigned* __restrict__ xsrc, const float* __restrict__ dis,
    const float* __restrict__ xf, unsigned* __restrict__ abuf,
    unsigned* __restrict__ t1s, int mode) {
    int node = (blockIdx.x * 256 + threadIdx.x) >> 6;
    if (node >= N_NODES) return;
    int lane = threadIdx.x & 63, h = lane >> 5, q = lane & 31;
    int b = off[node], end = off[node + 1];
    float acc0 = 0.f, acc1 = 0.f;
    for (; b + 7 < end; b += 8) {
        u64 v0 = rw[b + h], v1 = rw[b + h + 2], v2 = rw[b + h + 4], v3 = rw[b + h + 6];
        unsigned r0 = (unsigned)v0, r1 = (unsigned)v1, r2 = (unsigned)v2, r3 = (unsigned)v3;
        float a0 = __uint_as_float((unsigned)(v0 >> 32));
        float a1 = __uint_as_float((unsigned)(v1 >> 32));
        float a2 = __uint_as_float((unsigned)(v2 >> 32));
        float a3 = __uint_as_float((unsigned)(v3 >> 32));
        unsigned u0 = xsrc[r0 * 32 + q], u1 = xsrc[r1 * 32 + q];
        unsigned u2 = xsrc[r2 * 32 + q], u3 = xsrc[r3 * 32 + q];
        acc0 += a0 * bflo(u0) + a1 * bflo(u1) + a2 * bflo(u2) + a3 * bflo(u3);
        acc1 += a0 * bfhi(u0) + a1 * bfhi(u1) + a2 * bfhi(u2) + a3 * bfhi(u3);
    }
    for (; b + 1 < end; b += 2) {
        u64 v = rw[b + h];
        unsigned r = (unsigned)v;
        float a = __uint_as_float((unsigned)(v >> 32));
        unsigned u = xsrc[r * 32 + q];
        acc0 += a * bflo(u); acc1 += a * bfhi(u);
    }
    if (b < end && h == 0) {
        u64 v = rw[b];
        unsigned r = (unsigned)v;
        float a = __uint_as_float((unsigned)(v >> 32));
        unsigned u = xsrc[r * 32 + q];
        acc0 += a * bflo(u); acc1 += a * bfhi(u);
    }
    acc0 += __shfl_xor(acc0, 32, 64);
    acc1 += __shfl_xor(acc1, 32, 64);
    if (h == 0) {
        float di = dis[node];
        float t0 = -di * acc0, t1v = -di * acc1;
        if (mode == 0) {
            abuf[node * 96 + 32 + q] = packbf2(t0, t1v);
            t1s[node * 32 + q] = packbf2(di * t0, di * t1v);
        } else {
            float2 xv = ((const float2*)xf)[node * 32 + q];
            abuf[node * 96 + 64 + q] = packbf2(2.f * t0 - xv.x, 2.f * t1v - xv.y);
        }
    }
}

// ---- MFMA GEMM [50000x192]@[192x128] + GRU combine + head ----
__global__ __launch_bounds__(256) void k_gemm(
    const ushort_t* __restrict__ ab, const ushort_t* __restrict__ pbuf,
    const float* __restrict__ bxz, const float* __restrict__ bhz,
    const float* __restrict__ bxh, const float* __restrict__ bhh,
    const float* __restrict__ Wlin, const float* __restrict__ blin,
    float2* __restrict__ out) {
    __shared__ ushort_t bsh[24576];
    int tid = threadIdx.x;
    {
        uint4* s4 = (uint4*)bsh;
        const uint4* g4 = (const uint4*)pbuf;
        for (int i = tid; i < 3072; i += 256) s4[i] = g4[i];
    }
    __syncthreads();

    int wave = tid >> 6, lane = tid & 63;
    int quad = lane >> 4, m = lane & 15;
    int arow = blockIdx.x * 64 + wave * 16 + m;
    const ushort_t* ap = ab + (size_t)arow * 192 + quad * 8;

    f32x4 acc[8];
#pragma unroll
    for (int c = 0; c < 8; ++c) acc[c] = (f32x4){0.f, 0.f, 0.f, 0.f};
#pragma unroll
    for (int s = 0; s < 6; ++s) {
        bf16x8 af = *(const bf16x8*)(ap + s * 32);
#pragma unroll
        for (int c = 0; c < 8; ++c) {
            bf16x8 bfr = *(const bf16x8*)(bsh + ((c * 6 + s) * 64 + lane) * 8);
            acc[c] = __builtin_amdgcn_mfma_f32_16x16x32_bf16(af, bfr, acc[c], 0, 0, 0);
        }
    }
    float bzv[4], bhv[4], wl0[4], wl1[4];
#pragma unroll
    for (int c = 0; c < 4; ++c) {
        int col = c * 16 + m;
        bzv[c] = bxz[col] + bhz[col];
        bhv[c] = bxh[col] + bhh[col];
        wl0[c] = Wlin[2 * col];
        wl1[c] = Wlin[2 * col + 1];
    }
    float bl0 = blin[0], bl1 = blin[1];
#pragma unroll
    for (int i = 0; i < 4; ++i) {
        float p0 = 0.f, p1 = 0.f;
#pragma unroll
        for (int c = 0; c < 4; ++c) {
            float z  = fsigmoid(acc[c][i] + bzv[c]);
            float ht = ftanh(acc[c + 4][i] + bhv[c]);
            float t  = ftanh((1.f - z) * ht);
            p0 += t * wl0[c];
            p1 += t * wl1[c];
        }
        for (int o = 1; o <= 8; o <<= 1) {
            p0 += __shfl_xor(p0, o, 64);
            p1 += __shfl_xor(p1, o, 64);
        }
        int g = blockIdx.x * 64 + wave * 16 + quad * 4 + i;
        if (m == 0 && g < N_NODES)
            out[g] = make_float2(fsigmoid(p0 + bl0), fsigmoid(p1 + bl1));
    }
}

extern "C" void kernel_launch(void* const* d_in, const int* in_sizes, int n_in,
                              void* d_out, int out_size, void* d_ws, size_t ws_size,
                              hipStream_t stream) {
    const float* x    = (const float*)d_in[0];
    const int*   ei   = (const int*)d_in[1];
    const float* ew   = (const float*)d_in[2];
    const float* Wxz  = (const float*)d_in[3];
    const float* bxz  = (const float*)d_in[4];
    const float* bhz  = (const float*)d_in[6];
    const float* Wxh  = (const float*)d_in[11];
    const float* bxh  = (const float*)d_in[12];
    const float* bhh  = (const float*)d_in[14];
    const float* Wlin = (const float*)d_in[15];
    const float* blin = (const float*)d_in[16];

    float*    ws    = (float*)d_ws;
    unsigned* gcur  = (unsigned*)(ws + GCUR_O);
    float*    dis   = ws + DIS_O;
    int*      off   = (int*)(ws + OFF_O);
    unsigned* cslot = (unsigned*)(ws + CSLOT_O);
    unsigned* rslot = (unsigned*)(ws + RSLOT_O);
    u64*      rw    = (u64*)(ws + RW_O);
    unsigned* abuf  = (unsigned*)(ws + ABUF_O);
    ushort_t* pbuf  = (ushort_t*)(ws + PBUF_O);
    unsigned* xs    = (unsigned*)(ws + XS_O);    // aliases cslot
    unsigned* t1s   = (unsigned*)(ws + T1S_O);   // aliases rslot

    hipMemsetAsync(d_ws, 0, 512 * 4, stream);    // just the cursors

    k1<<<NB1 + 98 + 1, 512, 0, stream>>>(ei, ew, x, Wxz, Wxh, gcur, cslot, rslot, abuf, pbuf);
    k2<<<NBKT, 512, 0, stream>>>(ei, ew, x, gcur, cslot, rslot, dis, off, rw, xs);
    k_prop<<<12500, 256, 0, stream>>>(off, rw, xs, dis, x, abuf, t1s, 0);
    k_prop<<<12500, 256, 0, stream>>>(off, rw, t1s, dis, x, abuf, abuf, 1);
    k_gemm<<<782, 256, 0, stream>>>((const ushort_t*)abuf, pbuf, bxz, bhz, bxh, bhh,
                                    Wlin, blin, (float2*)d_out);
}

// Round 5
// 219.222 us; speedup vs baseline: 1.9591x; 1.0361x over previous
//
#include <hip/hip_runtime.h>
#include <hip/hip_bf16.h>

#define N_NODES 50000
#define N_EDGES 800000
#define NB1 400       // k1 bucketing blocks
#define CH  2000      // edges per k1 block (NB1*CH == N_EDGES)
#define NBKT 196      // MSD buckets = key>>8
#define CAP 8192      // slots per bucket (mean ~4082, +64 sigma headroom)
#define SORT_MAX 6144 // LDS sort capacity per bucket (+32 sigma)

typedef unsigned short ushort_t;
typedef unsigned long long u64;
typedef __attribute__((ext_vector_type(8))) short bf16x8;
typedef __attribute__((ext_vector_type(4))) float f32x4;

// ---------------- workspace layout (4-byte word offsets) ----------------
constexpr int GCUR_O  = 0;           // uint[512]: [0,196) col cursors, [256,452) row cursors
constexpr int DIS_O   = 512;         // float[50000]
constexpr int OFF_O   = 50512;       // int[50001]
constexpr int CSLOT_O = 100544;      // u64[196*8192] col buckets (w | col8 | row16); XS after k2
constexpr int RSLOT_O = 3311808;     // uint[196*8192] row buckets (w24 | row8); T1S after k2
constexpr int RW_O    = 4917440;     // u64[800000] CSR payload (w | row)
constexpr int ABUF_O  = 6517440;     // uint[50000*96] A=[x|tx1|tx2] bf16x2
constexpr int PBUF_O  = 11317440;    // ushort[24576] packed B
// total ~11.33M words = 45.3 MB
constexpr int XS_O    = CSLOT_O;     // uint[50000*32] xs = dis*x  (aliases col slots)
constexpr int T1S_O   = RSLOT_O;     // uint[50000*32] dis*tx1    (aliases row slots)

__device__ __forceinline__ ushort_t f32_to_bf16(float f) {
    unsigned u = __float_as_uint(f);
    u += 0x7fffu + ((u >> 16) & 1u);
    return (ushort_t)(u >> 16);
}
__device__ __forceinline__ float bflo(unsigned u) { return __uint_as_float(u << 16); }
__device__ __forceinline__ float bfhi(unsigned u) { return __uint_as_float(u & 0xffff0000u); }
__device__ __forceinline__ unsigned packbf2(float a, float b) {
    return (unsigned)f32_to_bf16(a) | ((unsigned)f32_to_bf16(b) << 16);
}
__device__ __forceinline__ float fsigmoid(float x) { return 1.f / (1.f + __expf(-x)); }
__device__ __forceinline__ float ftanh(float x) {
    x = fminf(15.f, fmaxf(-15.f, x));
    float e = __expf(2.f * x);
    return (e - 1.f) / (e + 1.f);
}

// ---- k1: dual MSD bucketing (col for CSR w/ full payload, row for deg) ----
// Payload carries (row, col&255, w) so ei/ew are never touched again.
__global__ __launch_bounds__(512) void k1(
    const int* __restrict__ ei, const float* __restrict__ ew,
    const float* __restrict__ x, const float* __restrict__ Wxz,
    const float* __restrict__ Wxh, unsigned* __restrict__ gcur,
    u64* __restrict__ cslot, unsigned* __restrict__ rslot,
    unsigned* __restrict__ abuf, ushort_t* __restrict__ pbuf) {
    int bid = blockIdx.x, t = threadIdx.x;
    if (bid < NB1) {
        __shared__ unsigned colbuf[CH], rowbuf[CH];
        __shared__ unsigned hc[256], hr[256], bc[256], br[256];
        if (t < 256) { hc[t] = 0; hr[t] = 0; }
        __syncthreads();
        int e0 = bid * CH;
        for (int i = t; i < CH; i += 512) {
            unsigned r = (unsigned)ei[e0 + i];
            unsigned c = (unsigned)ei[N_EDGES + e0 + i];
            rowbuf[i] = r;
            colbuf[i] = c;
            atomicAdd(&hc[c >> 8], 1u);
            atomicAdd(&hr[r >> 8], 1u);
        }
        __syncthreads();
        if (t < NBKT) {
            bc[t] = atomicAdd(&gcur[t], hc[t]);
            br[t] = atomicAdd(&gcur[256 + t], hr[t]);
        }
        __syncthreads();
        if (t < 256) { hc[t] = 0; hr[t] = 0; }   // reuse as local cursors
        __syncthreads();
        for (int i = t; i < CH; i += 512) {
            unsigned c = colbuf[i];
            unsigned r = rowbuf[i];
            unsigned w = __float_as_uint(ew[e0 + i]);
            unsigned dc = c >> 8;
            unsigned pc = bc[dc] + atomicAdd(&hc[dc], 1u);
            if (pc < CAP)
                cslot[dc * CAP + pc] = ((u64)w << 32) | ((c & 255u) << 16) | (r & 0xFFFFu);
            unsigned dr = r >> 8;
            unsigned pr = br[dr] + atomicAdd(&hr[dr], 1u);
            if (pr < CAP) rslot[dr * CAP + pr] = (w & 0xFFFFFF00u) | (r & 255u);
        }
    } else if (bid < NB1 + 98) {                 // plain-x bf16 cast into A cols [0,64)
        int n0 = (bid - NB1) * 512;
        for (int idx = t; idx < 512 * 32; idx += 512) {
            int n = n0 + (idx >> 5);
            if (n < N_NODES) {
                int q = idx & 31;
                float2 xv = ((const float2*)x)[n * 32 + q];
                abuf[n * 96 + q] = packbf2(xv.x, xv.y);
            }
        }
    } else {                                     // pack B into MFMA fragment order
        for (int idx = t; idx < 24576; idx += 512) {
            int k = idx >> 7, n = idx & 127;
            float v = (n < 64) ? Wxz[k * 64 + n] : Wxh[k * 64 + (n - 64)];
            int c = n >> 4, s = k >> 5, l = (((k >> 3) & 3) << 4) | (n & 15), j = k & 7;
            pbuf[((c * 6 + s) * 64 + l) * 8 + j] = f32_to_bf16(v);
        }
    }
}

// ---- k2: per-bucket LDS sort -> off + direct-scatter rw; then deg/dis/xs ----
__global__ __launch_bounds__(512) void k2(
    const float* __restrict__ x, const unsigned* __restrict__ gcur,
    const u64* __restrict__ cslot, const unsigned* __restrict__ rslot,
    float* __restrict__ dis, int* __restrict__ off,
    u64* __restrict__ rw, unsigned* __restrict__ xs) {
    int bid = blockIdx.x, t = threadIdx.x;
    __shared__ unsigned rawA[SORT_MAX], rawB[SORT_MAX];
    __shared__ unsigned hist[256], hsc[256], cur[256], gs[256];
    __shared__ float facc[256];

    // ---- phase A: sort col bucket bid by col&255 -> off + (row,w) CSR ----
    if (t < 256) {
        gs[t] = (t < NBKT) ? gcur[t] : 0u;
        hist[t] = 0;
    }
    __syncthreads();
    for (int o = 1; o < 256; o <<= 1) {          // inclusive scan of bucket sizes
        unsigned v = (t < 256 && t >= o) ? gs[t - o] : 0u;
        __syncthreads();
        if (t < 256) gs[t] += v;
        __syncthreads();
    }
    unsigned szb = gcur[bid];
    unsigned sz = min(szb, (unsigned)SORT_MAX);
    unsigned base = gs[bid] - szb;               // exclusive prefix
    for (unsigned i = t; i < sz; i += 512) {
        u64 v = cslot[bid * CAP + i];
        unsigned lo = (unsigned)v;
        rawA[i] = lo;
        rawB[i] = (unsigned)(v >> 32);
        atomicAdd(&hist[(lo >> 16) & 255u], 1u);
    }
    __syncthreads();
    unsigned h0 = (t < 256) ? hist[t] : 0u;
    if (t < 256) hsc[t] = h0;
    __syncthreads();
    for (int o = 1; o < 256; o <<= 1) {          // inclusive scan of digit hist
        unsigned v = (t < 256 && t >= o) ? hsc[t - o] : 0u;
        __syncthreads();
        if (t < 256) hsc[t] += v;
        __syncthreads();
    }
    if (t < 256) {
        hsc[t] -= h0;                            // exclusive
        cur[t] = 0u;
        int c = bid * 256 + t;
        if (c <= N_NODES) off[c] = (int)(base + hsc[t]);
    }
    __syncthreads();
    for (unsigned i = t; i < sz; i += 512) {     // position + direct global scatter
        unsigned lo = rawA[i];
        unsigned d = (lo >> 16) & 255u;
        unsigned p = hsc[d] + atomicAdd(&cur[d], 1u);
        rw[base + p] = ((u64)rawB[i] << 32) | (lo & 0xFFFFu);
    }
    __syncthreads();

    // ---- phase B: deg for rows [bid*256, +256) from row bucket, dis, xs ----
    if (t < 256) facc[t] = 0.f;
    __syncthreads();
    unsigned szr = min(gcur[256 + bid], (unsigned)CAP);
    for (unsigned i = t; i < szr; i += 512) {
        unsigned v = rslot[bid * CAP + i];
        atomicAdd(&facc[v & 255u], __uint_as_float(v & 0xFFFFFF00u));
    }
    __syncthreads();
    if (t < 256) {
        float d = facc[t];
        float r = d > 0.f ? rsqrtf(d) : 0.f;
        facc[t] = r;
        int n = bid * 256 + t;
        if (n < N_NODES) dis[n] = r;
    }
    __syncthreads();
    for (int idx = t; idx < 8192; idx += 512) {  // xs = dis*x, overwrites own col bucket
        int nl = idx >> 5, q = idx & 31;
        int n = bid * 256 + nl;
        if (n < N_NODES) {
            float2 xv = ((const float2*)x)[n * 32 + q];
            float r = facc[nl];
            xs[n * 32 + q] = packbf2(r * xv.x, r * xv.y);
        }
    }
}

// ---- prop: one wave per node; halves handle alternating edges ----
// mode 0: tx1 = -dis*sum(w*xs[row]); write abuf tx1 + t1s = dis*tx1
// mode 1: tx2 = 2*(-dis*sum(w*t1s[row])) - x(fp32); write abuf tx2
__global__ __launch_bounds__(256) void k_prop(
    const int* __restrict__ off, const u64* __restrict__ rw,
    const unsigned* __restrict__ xsrc, const float* __restrict__ dis,
    const float* __restrict__ xf, unsigned* __restrict__ abuf,
    unsigned* __restrict__ t1s, int mode) {
    int node = (blockIdx.x * 256 + threadIdx.x) >> 6;
    if (node >= N_NODES) return;
    int lane = threadIdx.x & 63, h = lane >> 5, q = lane & 31;
    int b = off[node], end = off[node + 1];
    float acc0 = 0.f, acc1 = 0.f;
    for (; b + 7 < end; b += 8) {
        u64 v0 = rw[b + h], v1 = rw[b + h + 2], v2 = rw[b + h + 4], v3 = rw[b + h + 6];
        unsigned r0 = (unsigned)v0 & 0xFFFFu, r1 = (unsigned)v1 & 0xFFFFu;
        unsigned r2 = (unsigned)v2 & 0xFFFFu, r3 = (unsigned)v3 & 0xFFFFu;
        float a0 = __uint_as_float((unsigned)(v0 >> 32));
        float a1 = __uint_as_float((unsigned)(v1 >> 32));
        float a2 = __uint_as_float((unsigned)(v2 >> 32));
        float a3 = __uint_as_float((unsigned)(v3 >> 32));
        unsigned u0 = xsrc[r0 * 32 + q], u1 = xsrc[r1 * 32 + q];
        unsigned u2 = xsrc[r2 * 32 + q], u3 = xsrc[r3 * 32 + q];
        acc0 += a0 * bflo(u0) + a1 * bflo(u1) + a2 * bflo(u2) + a3 * bflo(u3);
        acc1 += a0 * bfhi(u0) + a1 * bfhi(u1) + a2 * bfhi(u2) + a3 * bfhi(u3);
    }
    for (; b + 1 < end; b += 2) {
        u64 v = rw[b + h];
        unsigned r = (unsigned)v & 0xFFFFu;
        float a = __uint_as_float((unsigned)(v >> 32));
        unsigned u = xsrc[r * 32 + q];
        acc0 += a * bflo(u); acc1 += a * bfhi(u);
    }
    if (b < end && h == 0) {
        u64 v = rw[b];
        unsigned r = (unsigned)v & 0xFFFFu;
        float a = __uint_as_float((unsigned)(v >> 32));
        unsigned u = xsrc[r * 32 + q];
        acc0 += a * bflo(u); acc1 += a * bfhi(u);
    }
    acc0 += __shfl_xor(acc0, 32, 64);
    acc1 += __shfl_xor(acc1, 32, 64);
    if (h == 0) {
        float di = dis[node];
        float t0 = -di * acc0, t1v = -di * acc1;
        if (mode == 0) {
            abuf[node * 96 + 32 + q] = packbf2(t0, t1v);
            t1s[node * 32 + q] = packbf2(di * t0, di * t1v);
        } else {
            float2 xv = ((const float2*)xf)[node * 32 + q];
            abuf[node * 96 + 64 + q] = packbf2(2.f * t0 - xv.x, 2.f * t1v - xv.y);
        }
    }
}

// ---- MFMA GEMM [50000x192]@[192x128] + GRU combine + head ----
__global__ __launch_bounds__(256) void k_gemm(
    const ushort_t* __restrict__ ab, const ushort_t* __restrict__ pbuf,
    const float* __restrict__ bxz, const float* __restrict__ bhz,
    const float* __restrict__ bxh, const float* __restrict__ bhh,
    const float* __restrict__ Wlin, const float* __restrict__ blin,
    float2* __restrict__ out) {
    __shared__ ushort_t bsh[24576];
    int tid = threadIdx.x;
    {
        uint4* s4 = (uint4*)bsh;
        const uint4* g4 = (const uint4*)pbuf;
        for (int i = tid; i < 3072; i += 256) s4[i] = g4[i];
    }
    __syncthreads();

    int wave = tid >> 6, lane = tid & 63;
    int quad = lane >> 4, m = lane & 15;
    int arow = blockIdx.x * 64 + wave * 16 + m;
    const ushort_t* ap = ab + (size_t)arow * 192 + quad * 8;

    f32x4 acc[8];
#pragma unroll
    for (int c = 0; c < 8; ++c) acc[c] = (f32x4){0.f, 0.f, 0.f, 0.f};
#pragma unroll
    for (int s = 0; s < 6; ++s) {
        bf16x8 af = *(const bf16x8*)(ap + s * 32);
#pragma unroll
        for (int c = 0; c < 8; ++c) {
            bf16x8 bfr = *(const bf16x8*)(bsh + ((c * 6 + s) * 64 + lane) * 8);
            acc[c] = __builtin_amdgcn_mfma_f32_16x16x32_bf16(af, bfr, acc[c], 0, 0, 0);
        }
    }
    float bzv[4], bhv[4], wl0[4], wl1[4];
#pragma unroll
    for (int c = 0; c < 4; ++c) {
        int col = c * 16 + m;
        bzv[c] = bxz[col] + bhz[col];
        bhv[c] = bxh[col] + bhh[col];
        wl0[c] = Wlin[2 * col];
        wl1[c] = Wlin[2 * col + 1];
    }
    float bl0 = blin[0], bl1 = blin[1];
#pragma unroll
    for (int i = 0; i < 4; ++i) {
        float p0 = 0.f, p1 = 0.f;
#pragma unroll
        for (int c = 0; c < 4; ++c) {
            float z  = fsigmoid(acc[c][i] + bzv[c]);
            float ht = ftanh(acc[c + 4][i] + bhv[c]);
            float t  = ftanh((1.f - z) * ht);
            p0 += t * wl0[c];
            p1 += t * wl1[c];
        }
        for (int o = 1; o <= 8; o <<= 1) {
            p0 += __shfl_xor(p0, o, 64);
            p1 += __shfl_xor(p1, o, 64);
        }
        int g = blockIdx.x * 64 + wave * 16 + quad * 4 + i;
        if (m == 0 && g < N_NODES)
            out[g] = make_float2(fsigmoid(p0 + bl0), fsigmoid(p1 + bl1));
    }
}

extern "C" void kernel_launch(void* const* d_in, const int* in_sizes, int n_in,
                              void* d_out, int out_size, void* d_ws, size_t ws_size,
                              hipStream_t stream) {
    const float* x    = (const float*)d_in[0];
    const int*   ei   = (const int*)d_in[1];
    const float* ew   = (const float*)d_in[2];
    const float* Wxz  = (const float*)d_in[3];
    const float* bxz  = (const float*)d_in[4];
    const float* bhz  = (const float*)d_in[6];
    const float* Wxh  = (const float*)d_in[11];
    const float* bxh  = (const float*)d_in[12];
    const float* bhh  = (const float*)d_in[14];
    const float* Wlin = (const float*)d_in[15];
    const float* blin = (const float*)d_in[16];

    float*    ws    = (float*)d_ws;
    unsigned* gcur  = (unsigned*)(ws + GCUR_O);
    float*    dis   = ws + DIS_O;
    int*      off   = (int*)(ws + OFF_O);
    u64*      cslot = (u64*)(ws + CSLOT_O);
    unsigned* rslot = (unsigned*)(ws + RSLOT_O);
    u64*      rw    = (u64*)(ws + RW_O);
    unsigned* abuf  = (unsigned*)(ws + ABUF_O);
    ushort_t* pbuf  = (ushort_t*)(ws + PBUF_O);
    unsigned* xs    = (unsigned*)(ws + XS_O);    // aliases cslot
    unsigned* t1s   = (unsigned*)(ws + T1S_O);   // aliases rslot

    hipMemsetAsync(d_ws, 0, 512 * 4, stream);    // just the cursors

    k1<<<NB1 + 98 + 1, 512, 0, stream>>>(ei, ew, x, Wxz, Wxh, gcur, cslot, rslot, abuf, pbuf);
    k2<<<NBKT, 512, 0, stream>>>(x, gcur, cslot, rslot, dis, off, rw, xs);
    k_prop<<<12500, 256, 0, stream>>>(off, rw, xs, dis, x, abuf, t1s, 0);
    k_prop<<<12500, 256, 0, stream>>>(off, rw, t1s, dis, x, abuf, abuf, 1);
    k_gemm<<<782, 256, 0, stream>>>((const ushort_t*)abuf, pbuf, bxz, bhz, bxh, bhh,
                                    Wlin, blin, (float2*)d_out);
}